// Round 3
// baseline (198.078 us; speedup 1.0000x reference)
//
#include <hip/hip_runtime.h>
#include <math.h>

#define ALPHA 26
#define TPB 256
#define ROWF 26                  // stage row stride in floats (token row)
#define WAVEF (64 * ROWF)        // 1664 floats per wave-private region
#define BUFF (4 * WAVEF)         // 6656 floats per block-wide buffer
#define NBLK 768                 // 3 blocks/CU * 256 CUs (LDS-limited residency)

typedef __attribute__((ext_vector_type(8))) short short8;
typedef __attribute__((ext_vector_type(4))) float float4v;
typedef __attribute__((address_space(3))) float lds_f;
typedef const __attribute__((address_space(1))) float glb_f;

__device__ __forceinline__ unsigned short f2bf(float f) {
    unsigned u = __builtin_bit_cast(unsigned, f);
    u += 0x7FFFu + ((u >> 16) & 1u);          // round-to-nearest-even
    return (unsigned short)(u >> 16);
}

// Pre-kernel: row-L2-normalize rotor, emit TRANSPOSED bf16 B matrix padded to
// 32x32: rnbT[n][k] = bf16(rotor[k][n]/||rotor[k]||) for k,n<26, else 0.
// Transposed layout makes the main kernel's B-fragment load 2x dwordx4.
__global__ void rotor_norm_kernel(const float* __restrict__ rotor,
                                  unsigned short* __restrict__ rnbT) {
    __shared__ float inv[32];
    const int t = threadIdx.x;            // 64 threads
    if (t < 32) {
        float s = 0.f;
        if (t < ALPHA) {
            #pragma unroll
            for (int j = 0; j < ALPHA; ++j) {
                float v = rotor[t * ALPHA + j];
                s += v * v;
            }
            inv[t] = 1.0f / sqrtf(s);
        } else {
            inv[t] = 0.f;
        }
    }
    __syncthreads();
    const int n  = t >> 1;                // 0..31
    const int k0 = (t & 1) * 16;          // 0 or 16
    #pragma unroll
    for (int kk = 0; kk < 16; ++kk) {
        const int k = k0 + kk;
        float v = (k < ALPHA && n < ALPHA) ? rotor[k * ALPHA + n] * inv[k] : 0.f;
        rnbT[n * 32 + k] = f2bf(v);
    }
}

// Persistent grid-stride blocks, double-buffered LDS stage. Per tile:
//   wait vmcnt(7) [this tile's 8 loads retired; <=7 of last tile's stores
//   may stay in flight: in-order vmcnt retirement + compiler fence pinning
//   prefetch(i+1) above stores(i) makes W=7 exact-safe]
//   -> prefetch(t+1) -> gather-rotate A frags -> MFMA -> softmax -> 7 plain
//   float4/float2 stores (compiler-managed).
// All LDS regions wave-private: barrier-free.
__global__ __launch_bounds__(TPB, 3) void rotor_main(
        const float* __restrict__ x,
        const unsigned short* __restrict__ rnbT,
        float* __restrict__ out,
        int ntiles) {
    __shared__ float stage[2 * BUFF];     // 53248 B -> 3 blocks/CU

    const int tid  = threadIdx.x;
    const int lane = tid & 63;
    const int wave = tid >> 6;
    const int n15  = lane & 15;
    const int quad = lane >> 4;
    const int waveF = wave * WAVEF;

    // ---- B fragments: two contiguous 16B loads from transposed rnbT ----
    // B-operand layout (16x16x32): n = lane&15, k = quad*8 + j.
    // Plain loads: the compiler inserts its own waitcnt before first use.
    short8 bf0 = *(const short8*)(rnbT + n15 * 32 + quad * 8);
    short8 bf1 = *(const short8*)(rnbT + (n15 + 16) * 32 + quad * 8);

    int tile = blockIdx.x;
    if (tile >= ntiles) return;
    const int stride = gridDim.x;

    // Exactly 8 VMEM ops per tile prefetch, all direct-to-LDS.
    auto prefetch = [&](int buf, int t) {
        const float* gp = x + (long long)t * (TPB * ALPHA) + waveF;
        lds_f* lp = (lds_f*)&stage[buf * BUFF + waveF];
        #pragma unroll
        for (int it = 0; it < 6; ++it)
            __builtin_amdgcn_global_load_lds((glb_f*)(gp + it * 256 + lane * 4),
                                             lp + it * 256, 16, 0, 0);
        __builtin_amdgcn_global_load_lds((glb_f*)(gp + 1536 + lane), lp + 1536, 4, 0, 0);
        __builtin_amdgcn_global_load_lds((glb_f*)(gp + 1600 + lane), lp + 1600, 4, 0, 0);
    };

    prefetch(0, tile);

    int i = 0;
    for (; tile < ntiles; tile += stride, ++i) {
        // Wait for THIS tile's 8 loads. i=0: only those are outstanding.
        // Steady state: outstanding = [P(i) (8, older), S(i-1) (7, younger)];
        // vmcnt(7) retires >=8 oldest => all P(i) landed, stores ride on.
        if (i == 0) asm volatile("s_waitcnt vmcnt(0)" ::: "memory");
        else        asm volatile("s_waitcnt vmcnt(7)" ::: "memory");

        const int cur = i & 1;
        const int tnext = tile + stride;
        if (tnext < ntiles) prefetch(cur ^ 1, tnext);
        // Zero-instruction fence: keeps this iteration's stores (below) from
        // hoisting above the prefetch -> issue order P(i+1) < S(i) holds.
        asm volatile("" ::: "memory");

        const int sbase   = cur * BUFF + waveF;
        const int tokBase = tile * TPB + wave * 64;

        // ---- GEMM: 4 M-tiles x 2 N-tiles of mfma_f32_16x16x32_bf16 ----
        float4v accA[4], accB[4];
        #pragma unroll
        for (int m = 0; m < 4; ++m) {
            accA[m] = (float4v){0.f, 0.f, 0.f, 0.f};
            accB[m] = (float4v){0.f, 0.f, 0.f, 0.f};
        }

        #pragma unroll
        for (int m = 0; m < 4; ++m) {
            // A layout: this lane supplies token m*16 + n15, k = quad*8 + j.
            const int tok = tokBase + m * 16 + n15;
            const int r = (tok & 8191) % 26;          // S = 8192, position == 1
            const int rowOff = sbase + (m * 16 + n15) * ROWF;
            const int k0 = quad * 8;
            int idx0 = k0 - r; if (idx0 < 0) idx0 += 26;   // in [0,25]

            short8 af;
            #pragma unroll
            for (int j = 0; j < 8; ++j) {
                int idx = idx0 + j; if (idx >= 26) idx -= 26;  // stays in [0,25]
                // No K-pad mask needed: rnbT rows k>=26 are exact zeros.
                af[j] = (short)f2bf(stage[rowOff + idx]);
            }
            accA[m] = __builtin_amdgcn_mfma_f32_16x16x32_bf16(af, bf0, accA[m], 0, 0, 0);
            accB[m] = __builtin_amdgcn_mfma_f32_16x16x32_bf16(af, bf1, accB[m], 0, 0, 0);
        }

        // ---- C writeback (C/D: col=lane&15, row=quad*4+reg), wave-private ----
        // Plain LDS stores; compiler inserts lgkm waits for the softmax reads.
        #pragma unroll
        for (int m = 0; m < 4; ++m) {
            #pragma unroll
            for (int rg = 0; rg < 4; ++rg) {
                const int base = sbase + (m * 16 + quad * 4 + rg) * ROWF;
                stage[base + n15] = accA[m][rg];
                if (n15 < ALPHA - 16)                  // cols 16..25 only
                    stage[base + 16 + n15] = accB[m][rg];
            }
        }

        // ---- Per-lane softmax over own token's 26 logits ----
        const float* myrow = &stage[sbase + lane * ROWF];
        float v[ALPHA];
        #pragma unroll
        for (int j = 0; j < ALPHA; ++j) v[j] = myrow[j];
        float mx = v[0];
        #pragma unroll
        for (int j = 1; j < ALPHA; ++j) mx = fmaxf(mx, v[j]);
        float sum = 0.f;
        #pragma unroll
        for (int j = 0; j < ALPHA; ++j) { v[j] = __expf(v[j] - mx); sum += v[j]; }
        float inv = 1.0f / sum;
        float* wrow = &stage[sbase + lane * ROWF];
        #pragma unroll
        for (int j = 0; j < ALPHA; ++j) wrow[j] = v[j] * inv;

        // ---- Coalesced stores (plain; exactly 7 VMEM ops per wave) ----
        float* gout = out + (long long)tile * (TPB * ALPHA) + waveF;
        #pragma unroll
        for (int it = 0; it < 6; ++it) {
            float4 d = *(const float4*)&stage[sbase + it * 256 + lane * 4];
            *(float4*)(gout + it * 256 + lane * 4) = d;
        }
        {
            float2 d = *(const float2*)&stage[sbase + 1536 + lane * 2];
            *(float2*)(gout + 1536 + lane * 2) = d;
        }
    }
}

extern "C" void kernel_launch(void* const* d_in, const int* in_sizes, int n_in,
                              void* d_out, int out_size, void* d_ws, size_t ws_size,
                              hipStream_t stream) {
    const float* x     = (const float*)d_in[0];   // [128, 8192, 26] fp32
    const float* rotor = (const float*)d_in[1];   // [26, 26] fp32
    float* out = (float*)d_out;                   // [128, 8192, 26] fp32
    unsigned short* rnbT = (unsigned short*)d_ws; // bf16 B^T matrix, 32x32 = 2 KB

    rotor_norm_kernel<<<1, 64, 0, stream>>>(rotor, rnbT);

    const int tokens = out_size / ALPHA;          // 1,048,576
    const int tiles  = tokens / TPB;              // 4096
    const int grid   = (tiles < NBLK) ? tiles : NBLK;
    rotor_main<<<grid, TPB, 0, stream>>>(x, rnbT, out, tiles);
}